// Round 5
// baseline (320.446 us; speedup 1.0000x reference)
//
#include <hip/hip_runtime.h>

// ---------------- problem constants ----------------
// B=4096 batch, D=2048 dim, H=3 hidden layers, O=1 output
#define BB 4096
#define DD 2048

typedef float f32x4 __attribute__((ext_vector_type(4)));
typedef __bf16 bf16x8 __attribute__((ext_vector_type(8)));

typedef __attribute__((address_space(1))) unsigned int gl_u32;
typedef __attribute__((address_space(3))) unsigned int lds_u32;

#define GLOAD_LDS16(gptr, sptr) \
  __builtin_amdgcn_global_load_lds((gl_u32*)(void*)(gptr), (lds_u32*)(sptr), 16, 0, 0)

// raw barrier with compiler memory fence (does NOT force vmcnt(0) drain like
// __syncthreads) — required for counted-vmcnt pipelining (T3/T4).
#define SBAR_MEM() asm volatile("s_barrier" ::: "memory")
#define VMCNT(n)   asm volatile("s_waitcnt vmcnt(" #n ")" ::: "memory")

__device__ __forceinline__ unsigned short f2bf(float f) {
  unsigned int u = __float_as_uint(f);
  u += 0x7fffu + ((u >> 16) & 1u);   // round-to-nearest-even
  return (unsigned short)(u >> 16);
}

// fast softplus: v_exp_f32 + v_log_f32 (quarter-rate HW ops).
__device__ __forceinline__ float sp(float x) {
  float t = __expf(-fabsf(x));
  return fmaxf(x, 0.0f) + __logf(1.0f + t);
}

__device__ __forceinline__ void prep_w_vec4(
    const float* __restrict__ mu, const float* __restrict__ rho,
    const float* __restrict__ eps, unsigned short* __restrict__ Wh,
    long long i)
{
  float4 m = ((const float4*)mu)[i];
  float4 r = ((const float4*)rho)[i];
  float4 e = ((const float4*)eps)[i];
  ushort4 o;
  o.x = f2bf(m.x + e.x * sp(r.x));
  o.y = f2bf(m.y + e.y * sp(r.y));
  o.z = f2bf(m.z + e.z * sp(r.z));
  o.w = f2bf(m.w + e.w * sp(r.w));
  ((ushort4*)Wh)[i] = o;
}

__device__ __forceinline__ void prep_f32_vec4(
    const float* __restrict__ mu, const float* __restrict__ rho,
    const float* __restrict__ eps, float* __restrict__ out, long long i)
{
  float4 m = ((const float4*)mu)[i];
  float4 r = ((const float4*)rho)[i];
  float4 e = ((const float4*)eps)[i];
  float4 o;
  o.x = m.x + e.x * sp(r.x);
  o.y = m.y + e.y * sp(r.y);
  o.z = m.z + e.z * sp(r.z);
  o.w = m.w + e.w * sp(r.w);
  ((float4*)out)[i] = o;
}

// ---------------- prep0: only what gemm1 needs: W0->bf16, x->bf16, b0 ----
// 512 threads/block. Regions: [0,512) W0 | [512,1536) x | 1536 b0
__global__ __launch_bounds__(512) void prep0_kernel(
    const float* __restrict__ x,
    const float* __restrict__ wmuh, const float* __restrict__ wrhoh,
    const float* __restrict__ bmuh, const float* __restrict__ brhoh,
    const float* __restrict__ epswh, const float* __restrict__ epsbh,
    unsigned short* __restrict__ Wh, unsigned short* __restrict__ Xb,
    float* __restrict__ bh)
{
  const int b = blockIdx.x;
  const int t = threadIdx.x;
  if (b < 512) {
    long long base = (long long)b * 2048 + t;
    #pragma unroll
    for (int j = 0; j < 4; ++j)
      prep_w_vec4(wmuh, wrhoh, epswh, Wh, base + j * 512);
    return;
  }
  if (b < 1536) {
    long long base = (long long)(b - 512) * 2048 + t;
    #pragma unroll
    for (int j = 0; j < 4; ++j) {
      float4 v = ((const float4*)x)[base + j * 512];
      ushort4 o;
      o.x = f2bf(v.x); o.y = f2bf(v.y); o.z = f2bf(v.z); o.w = f2bf(v.w);
      ((ushort4*)Xb)[base + j * 512] = o;
    }
    return;
  }
  // b == 1536: bias layer 0 (512 vec4)
  prep_f32_vec4(bmuh, brhoh, epsbh, bh, t);
}

// ---------------- R9 GEMM core: 256x128 tile, 3-buffer ring, counted vmcnt
// (R10 = identical resubmit of R9: the R9 bench died to a container infra
// flake with zero signal; audit found no hang/fault mechanism — barrier
// counts wave-uniform, vmcnt ledger closed, LDS 144K<160K, no OOB.)
//   BM=256 BN=128 BK=64 -> 16x16=256 blocks = 1/CU (LDS-forced). 8 waves,
//   wave tile 64x64 (acc[4][4]) -> 32 MFMA : 16 ds_read_b128 per K-tile.
//   3 LDS buffers (144 KiB), stage K-tile k+2 while computing k,
//   s_waitcnt vmcnt(12) (counted — never 0 in steady loop, T4), raw
//   s_barrier pairs (T3), setprio around MFMA clusters (T5).
// Race audit: buffer staged at iter k was last read at iter k-1, whose reads
// complete before its trailing barrier; vmcnt(12)+barrier certify buffer k
// before any wave reads it. XOR swizzle (T2) unchanged from verified core.
#define NGEMM 256
#define ATILE 16384   // 256*64 elems (A panel)
#define BUFE  24576   // + 128*64 (B panel)

struct Coords256 { int m0, n0; int srow[4], sgc[4]; };

__device__ __forceinline__ Coords256 coords256(int id, int t) {
  Coords256 g;
  const int p = id & 7;        // XCD patch (L2 locality)
  const int i4 = id >> 3;      // 0..31 within patch
  const int mt = (p & 3) * 4 + (i4 & 3);     // 0..15
  const int nt = (p >> 2) * 8 + (i4 >> 2);   // 0..15
  g.m0 = mt * 256;
  g.n0 = nt * 128;
  #pragma unroll
  for (int i = 0; i < 4; ++i) {
    int c = i * 512 + t;
    g.srow[i] = c >> 3;                      // 0..255
    g.sgc[i] = (c & 7) ^ (g.srow[i] & 7);    // XOR swizzle folded into gsrc
  }
  return g;
}

__device__ __forceinline__ void stage_tile(
    const unsigned short* __restrict__ A, const unsigned short* __restrict__ W,
    unsigned short* buf, const Coords256& gc, int kt, int t)
{
  #pragma unroll
  for (int i = 0; i < 4; ++i) {   // A panel: 256 rows x 64 cols
    int c = i * 512 + t;
    const unsigned short* ga = A + (size_t)(gc.m0 + gc.srow[i]) * DD + kt + gc.sgc[i] * 8;
    GLOAD_LDS16(ga, &buf[c * 8]);
  }
  #pragma unroll
  for (int i = 0; i < 2; ++i) {   // B panel: 128 rows x 64 cols
    int c = i * 512 + t;
    const unsigned short* gb = W + (size_t)(gc.n0 + gc.srow[i]) * DD + kt + gc.sgc[i] * 8;
    GLOAD_LDS16(gb, &buf[ATILE + c * 8]);
  }
}

__device__ __forceinline__ void compute_ktile(
    const unsigned short* buf, int wm, int wn, int lq, int lr,
    f32x4 (&acc)[4][4])
{
  #pragma unroll
  for (int s = 0; s < 2; ++s) {
    bf16x8 af[4], bfv[4];
    const int g = s * 4 + lq;
    const int go = (g ^ (lr & 7)) * 8;   // row&7 == lr&7 (wm*64, i*16 are mult of 8)
    #pragma unroll
    for (int i = 0; i < 4; ++i) {
      int ra = wm * 64 + i * 16 + lr;
      af[i] = *(const bf16x8*)&buf[ra * 64 + go];
    }
    #pragma unroll
    for (int j = 0; j < 4; ++j) {
      int rb = wn * 64 + j * 16 + lr;
      bfv[j] = *(const bf16x8*)&buf[ATILE + rb * 64 + go];
    }
    __builtin_amdgcn_s_setprio(1);
    #pragma unroll
    for (int i = 0; i < 4; ++i)
      #pragma unroll
      for (int j = 0; j < 4; ++j)
        acc[i][j] = __builtin_amdgcn_mfma_f32_16x16x32_bf16(af[i], bfv[j], acc[i][j], 0, 0, 0);
    __builtin_amdgcn_s_setprio(0);
  }
}

__device__ __forceinline__ void gemm_mainloop256(
    const unsigned short* __restrict__ A, const unsigned short* __restrict__ W,
    unsigned short (*lds)[BUFE], const Coords256& gc, int t, f32x4 (&acc)[4][4])
{
  const int l = t & 63, lq = l >> 4, lr = l & 15;
  const int w = t >> 6, wm = w & 3, wn = w >> 2;
  unsigned short *p0 = lds[0], *p1 = lds[1], *p2 = lds[2];
  stage_tile(A, W, p0, gc, 0, t);
  stage_tile(A, W, p1, gc, 64, t);
  for (int k = 0; k < 32; ++k) {
    if (k < 30) {
      stage_tile(A, W, p2, gc, (k + 2) * 64, t);
      VMCNT(12);                 // wait tile k done; k+1/k+2 stay in flight
    } else if (k == 30) {
      VMCNT(6);
    } else {
      VMCNT(0);
    }
    SBAR_MEM();                  // all waves' tile-k loads complete
    compute_ktile(p0, wm, wn, lq, lr, acc);
    SBAR_MEM();                  // all waves done reading p0 -> stageable
    unsigned short* tmp = p0; p0 = p1; p1 = p2; p2 = tmp;
  }
}

__device__ __forceinline__ void epilogue_store256(
    const Coords256& gc, int t, f32x4 (&acc)[4][4],
    const float* __restrict__ bias, unsigned short* __restrict__ C)
{
  const int l = t & 63, lq = l >> 4, lr = l & 15;
  const int w = t >> 6, wm = w & 3, wn = w >> 2;
  #pragma unroll
  for (int j = 0; j < 4; ++j) {
    int n = gc.n0 + wn * 64 + j * 16 + lr;
    float bv = bias[n];
    #pragma unroll
    for (int i = 0; i < 4; ++i) {
      int mbase = gc.m0 + wm * 64 + i * 16 + lq * 4;
      #pragma unroll
      for (int r = 0; r < 4; ++r) {
        float v = fmaxf(acc[i][j][r] + bv, 0.0f);
        C[(size_t)(mbase + r) * DD + n] = f2bf(v);
      }
    }
  }
}

// gemm1 + fused prep tail (W1/W2/b1/b2/wo) — R0 structure, new GEMM core
__global__ __launch_bounds__(512, 2) void gemm_relu_fused_kernel(
    const unsigned short* __restrict__ A,
    const unsigned short* __restrict__ W,
    const float* __restrict__ bias,
    unsigned short* __restrict__ C,
    const float* __restrict__ wmuh, const float* __restrict__ wrhoh,
    const float* __restrict__ bmuh, const float* __restrict__ brhoh,
    const float* __restrict__ wmuo, const float* __restrict__ wrhoo,
    const float* __restrict__ epswh, const float* __restrict__ epsbh,
    const float* __restrict__ epswo,
    unsigned short* __restrict__ Wh, float* __restrict__ bh,
    float* __restrict__ wo)
{
  __shared__ unsigned short lds[3][BUFE];   // 144 KiB -> 1 block/CU

  const int id = blockIdx.x;
  const int t = threadIdx.x;   // 0..511

  if (id >= NGEMM) {
    const int pb = id - NGEMM;
    if (pb < 1024) {
      // W1,W2: vec4 idx 1048576..3145727, 2048/block, 4/thread
      long long base = 1048576LL + (long long)pb * 2048 + t;
      #pragma unroll
      for (int j = 0; j < 4; ++j)
        prep_w_vec4(wmuh, wrhoh, epswh, Wh, base + j * 512);
      return;
    }
    // smalls: b1,b2 (bh vec4 512..1535), wo (512 vec4, t<512 exactly covers)
    #pragma unroll
    for (int j = 0; j < 2; ++j)
      prep_f32_vec4(bmuh, brhoh, epsbh, bh, 512 + j * 512 + t);
    prep_f32_vec4(wmuo, wrhoo, epswo, wo, t);
    return;
  }

  Coords256 gc = coords256(id, t);
  f32x4 acc[4][4] = {};
  gemm_mainloop256(A, W, lds, gc, t, acc);
  epilogue_store256(gc, t, acc, bias, C);
}

// plain gemm (layer 2)
__global__ __launch_bounds__(512, 2) void gemm_relu_kernel(
    const unsigned short* __restrict__ A,
    const unsigned short* __restrict__ W,
    const float* __restrict__ bias,
    unsigned short* __restrict__ C)
{
  __shared__ unsigned short lds[3][BUFE];
  const int t = threadIdx.x;
  Coords256 gc = coords256(blockIdx.x, t);
  f32x4 acc[4][4] = {};
  gemm_mainloop256(A, W, lds, gc, t, acc);
  epilogue_store256(gc, t, acc, bias, C);
}

// layer 3 + dot with wo, NO atomics / NO d_out access:
// Pbuf[nt*4096 + m] = sum_{n in this block's 128 cols} relu(acc+b2[n])*wo[n]
__global__ __launch_bounds__(512, 2) void gemm_relu_dot_kernel(
    const unsigned short* __restrict__ A,
    const unsigned short* __restrict__ W,
    const float* __restrict__ bias,
    const float* __restrict__ wo,
    float* __restrict__ Pbuf)
{
  __shared__ unsigned short lds[3][BUFE];
  const int t = threadIdx.x;

  Coords256 gc = coords256(blockIdx.x, t);
  f32x4 acc[4][4] = {};
  gemm_mainloop256(A, W, lds, gc, t, acc);

  const int l = t & 63, lq = l >> 4, lr = l & 15;
  const int w = t >> 6, wm = w & 3, wn = w >> 2;

  float bv[4], wv[4];
  #pragma unroll
  for (int j = 0; j < 4; ++j) {
    int n = gc.n0 + wn * 64 + j * 16 + lr;
    bv[j] = bias[n];
    wv[j] = wo[n];
  }
  float partial[4][4];
  #pragma unroll
  for (int i = 0; i < 4; ++i)
    #pragma unroll
    for (int r = 0; r < 4; ++r) {
      float s = 0.0f;
      #pragma unroll
      for (int j = 0; j < 4; ++j)
        s += fmaxf(acc[i][j][r] + bv[j], 0.0f) * wv[j];
      partial[i][r] = s;
    }

  // butterfly over lr (lane bits 0..3)
  #pragma unroll
  for (int d = 1; d <= 8; d <<= 1)
    #pragma unroll
    for (int i = 0; i < 4; ++i)
      #pragma unroll
      for (int r = 0; r < 4; ++r)
        partial[i][r] += __shfl_xor(partial[i][r], d, 64);

  // cross-wave reduce via LDS (mainloop ended with trailing s_barrier:
  // all waves are past every read of lds[0]).
  float* sRed = (float*)lds;   // [256 rows][2 col-halves]
  if (lr == 0) {
    #pragma unroll
    for (int i = 0; i < 4; ++i)
      #pragma unroll
      for (int r = 0; r < 4; ++r) {
        int row = wm * 64 + i * 16 + lq * 4 + r;   // 0..255 in tile
        sRed[row * 2 + wn] = partial[i][r];
      }
  }
  __syncthreads();
  if (t < 256) {
    float s = sRed[t * 2 + 0] + sRed[t * 2 + 1];
    int nt = gc.n0 >> 7;
    Pbuf[nt * BB + gc.m0 + t] = s;
  }
}

// final reduce: out[m] = bo + sum_{nt<16} Pbuf[nt*4096+m]  (overwrite-only)
__global__ __launch_bounds__(256) void reduce_out_kernel(
    const float* __restrict__ Pbuf,
    const float* __restrict__ bmuo, const float* __restrict__ brhoo,
    const float* __restrict__ epsbo,
    float* __restrict__ out)
{
  const int m = blockIdx.x * 256 + threadIdx.x;
  float s = bmuo[0] + epsbo[0] * sp(brhoo[0]);
  #pragma unroll
  for (int nt = 0; nt < 16; ++nt)
    s += Pbuf[nt * BB + m];
  out[m] = s;
}

// ---------------- launch ----------------
extern "C" void kernel_launch(void* const* d_in, const int* in_sizes, int n_in,
                              void* d_out, int out_size, void* d_ws, size_t ws_size,
                              hipStream_t stream) {
  const float* x     = (const float*)d_in[0];
  const float* wmuh  = (const float*)d_in[1];
  const float* wrhoh = (const float*)d_in[2];
  const float* bmuh  = (const float*)d_in[3];
  const float* brhoh = (const float*)d_in[4];
  const float* wmuo  = (const float*)d_in[5];
  const float* wrhoo = (const float*)d_in[6];
  const float* bmuo  = (const float*)d_in[7];
  const float* brhoo = (const float*)d_in[8];
  const float* epswh = (const float*)d_in[9];
  const float* epsbh = (const float*)d_in[10];
  const float* epswo = (const float*)d_in[11];
  const float* epsbo = (const float*)d_in[12];

  char* ws = (char*)d_ws;
  unsigned short* Wh = (unsigned short*)(ws);                       // 25165824 B
  unsigned short* Xb = (unsigned short*)(ws + 25165824);            // 16777216 B
  unsigned short* Ha = (unsigned short*)(ws + 25165824 + 16777216);
  unsigned short* Hb = (unsigned short*)(ws + 25165824 + 2 * 16777216);
  float* bh   = (float*)(ws + 25165824 + 3 * 16777216);             // 24576 B
  float* wo   = (float*)(ws + 25165824 + 3 * 16777216 + 24576);     // 8192 B
  float* Pbuf = (float*)(ws + 25165824 + 3 * 16777216 + 24576 + 8192); // 262144 B

  prep0_kernel<<<1537, 512, 0, stream>>>(
      x, wmuh, wrhoh, bmuh, brhoh, epswh, epsbh, Wh, Xb, bh);

  gemm_relu_fused_kernel<<<NGEMM + 1025, 512, 0, stream>>>(
      Xb, Wh, bh, Ha,
      wmuh, wrhoh, bmuh, brhoh, wmuo, wrhoo,
      epswh, epsbh, epswo, Wh, bh, wo);

  gemm_relu_kernel<<<NGEMM, 512, 0, stream>>>(Ha, Wh + 1 * 4194304, bh + DD, Hb);

  gemm_relu_dot_kernel<<<NGEMM, 512, 0, stream>>>(
      Hb, Wh + 2 * 4194304, bh + 2 * DD, wo, Pbuf);

  reduce_out_kernel<<<BB / 256, 256, 0, stream>>>(
      Pbuf, bmuo, brhoo, epsbo, (float*)d_out);
}